// Round 10
// baseline (427.550 us; speedup 1.0000x reference)
//
#include <hip/hip_runtime.h>
#include <stdint.h>

#define NN 8192
#define DD 256

typedef __attribute__((ext_vector_type(8))) short short8;
typedef __attribute__((ext_vector_type(4))) float f32x4;

typedef const uint32_t __attribute__((address_space(1)))* gbl_ptr_t;
typedef uint32_t __attribute__((address_space(3)))* lds_ptr_t;

__device__ __forceinline__ void gl_lds16(const void* g, const void* l) {
    __builtin_amdgcn_global_load_lds((gbl_ptr_t)(uintptr_t)g,
                                     (lds_ptr_t)(uintptr_t)l, 16, 0, 0);
}

__device__ __forceinline__ unsigned short f32_to_bf16(float f) {
    uint32_t u = __float_as_uint(f);
    u += 0x7fff + ((u >> 16) & 1);   // RNE
    return (unsigned short)(u >> 16);
}
__device__ __forceinline__ float bf16_to_f32(unsigned short h) {
    return __uint_as_float(((uint32_t)h) << 16);
}

// counted waits + raw barrier (rule 18: sched_barrier after asm waitcnt)
#define WAITVM8()  do { asm volatile("s_waitcnt vmcnt(8)" ::: "memory"); \
                        __builtin_amdgcn_sched_barrier(0); } while (0)
#define WAITVM0()  do { asm volatile("s_waitcnt vmcnt(0)" ::: "memory"); \
                        __builtin_amdgcn_sched_barrier(0); } while (0)
#define WAITLG0()  do { asm volatile("s_waitcnt lgkmcnt(0)" ::: "memory"); \
                        __builtin_amdgcn_sched_barrier(0); } while (0)
#define BAR()      __builtin_amdgcn_s_barrier()

// ---------------------------------------------------------------------------
// prep: hi/lo bf16 split stored PRE-SWIZZLED for BK=32 staging (rule #21:
// linear gl_lds dest + inverse-swizzled global source + XOR on ds_read).
// Within each 32-col K-block, 16B-chunk g -> slot g ^ (r&3).
// ---------------------------------------------------------------------------
__global__ void prep_kernel(const float* __restrict__ x,
                            unsigned short* __restrict__ hi,
                            unsigned short* __restrict__ lo,
                            float* __restrict__ sq,
                            float* __restrict__ denom) {
    const int r = blockIdx.x;
    const int t = threadIdx.x;                 // 0..255 = column
    float v = x[(size_t)r * DD + t];
    unsigned short h = f32_to_bf16(v);
    unsigned short l = f32_to_bf16(v - bf16_to_f32(h));
    int csw = (t & ~31) | ((((t >> 3) & 3) ^ (r & 3)) << 3) | (t & 7);
    hi[(size_t)r * DD + csw] = h;
    lo[(size_t)r * DD + csw] = l;

    float s = v * v;
    #pragma unroll
    for (int m = 32; m >= 1; m >>= 1) s += __shfl_xor(s, m, 64);
    __shared__ float ws[4];
    if ((t & 63) == 0) ws[t >> 6] = s;
    __syncthreads();
    if (t == 0) {
        sq[r] = ws[0] + ws[1] + ws[2] + ws[3];
        denom[r] = 0.0f;
    }
}

// ---------------------------------------------------------------------------
// Shared pipelined K-loop: BK=32, 8 steps, double-buffered 2x32KB LDS,
// raw barriers + counted vmcnt(8) (T3/T4 minimum).  Per step:
//   frag-read buf[p] -> 48 MFMA -> lgkm0+BAR (reads done globally)
//   -> STAGE(t+2 -> buf[p]) -> vmcnt(8) (stage t+1 done) -> BAR.
// Buffer layout (shorts): p*16384 + {Ahi 0, Alo 4096, Bhi 8192, Blo 12288}.
// K order identical to the R7 loop -> bit-identical results.
// ---------------------------------------------------------------------------
#define STAGE(st, p) do {                                                     \
    _Pragma("unroll")                                                         \
    for (int c = 0; c < 2; ++c) {                                             \
        int lin  = c * 256 + tid;                                             \
        int row  = lin >> 2;                                                  \
        int col8 = lin & 3;                                                   \
        size_t gA = (size_t)(row0 + row) * DD + (st) * 32 + col8 * 8;         \
        size_t gB = (size_t)(col0 + row) * DD + (st) * 32 + col8 * 8;         \
        char* bse = (char*)lds + (p) * 32768 + (c * 256 + wid * 64) * 16;     \
        gl_lds16(hi + gA, bse);                                               \
        gl_lds16(lo + gA, bse + 8192);                                        \
        gl_lds16(hi + gB, bse + 16384);                                       \
        gl_lds16(lo + gB, bse + 24576);                                       \
    } } while (0)

#define DIST_KLOOP()                                                          \
    STAGE(0, 0);                                                              \
    STAGE(1, 1);                                                              \
    WAITVM8(); BAR();                                                         \
    _Pragma("unroll")                                                         \
    for (int t = 0; t < 8; ++t) {                                             \
        const int p = t & 1;                                                  \
        unsigned short* L = lds + p * 16384;                                  \
        short8 ah[4], al[4], bh[4], bl[4];                                    \
        _Pragma("unroll")                                                     \
        for (int fm = 0; fm < 4; ++fm) {                                      \
            int row = wm * 64 + fm * 16 + l15;                                \
            int cb  = (lk * 16) ^ ((row & 3) << 4);                           \
            int off = row * 32 + (cb >> 1);                                   \
            ah[fm] = *(const short8*)(L + off);                               \
            al[fm] = *(const short8*)(L + 4096 + off);                        \
        }                                                                     \
        _Pragma("unroll")                                                     \
        for (int fn = 0; fn < 4; ++fn) {                                      \
            int row = wn * 64 + fn * 16 + l15;                                \
            int cb  = (lk * 16) ^ ((row & 3) << 4);                           \
            int off = row * 32 + (cb >> 1);                                   \
            bh[fn] = *(const short8*)(L + 8192 + off);                        \
            bl[fn] = *(const short8*)(L + 12288 + off);                       \
        }                                                                     \
        _Pragma("unroll")                                                     \
        for (int fm = 0; fm < 4; ++fm)                                        \
            _Pragma("unroll")                                                 \
            for (int fn = 0; fn < 4; ++fn) {                                  \
                acc[fm][fn] = __builtin_amdgcn_mfma_f32_16x16x32_bf16(        \
                    ah[fm], bh[fn], acc[fm][fn], 0, 0, 0);                    \
                acc[fm][fn] = __builtin_amdgcn_mfma_f32_16x16x32_bf16(        \
                    ah[fm], bl[fn], acc[fm][fn], 0, 0, 0);                    \
                acc[fm][fn] = __builtin_amdgcn_mfma_f32_16x16x32_bf16(        \
                    al[fm], bh[fn], acc[fm][fn], 0, 0, 0);                    \
            }                                                                 \
        WAITLG0(); BAR();               /* all waves done reading buf[p] */   \
        if (t + 2 < 8) STAGE(t + 2, p); /* overwrite now safe */              \
        if (t < 6)      { WAITVM8(); }  /* stage(t+1) done, t+2 in flight */  \
        else if (t == 6){ WAITVM0(); }  /* tail drain */                      \
        if (t < 7) BAR();               /* buf[p^1] globally visible */       \
    }

#define DIST_PROLOG()                                                         \
    const int tid  = threadIdx.x;                                             \
    const int lane = tid & 63;                                                \
    const int wid  = tid >> 6;                                                \
    const int wm = wid >> 1, wn = wid & 1;                                    \
    const int l15 = lane & 15, lk = lane >> 4;                                \
    /* XCD-chunked tri mapping: 2080 = 8 XCDs x 260 contiguous tiles */       \
    int wg = (blockIdx.x & 7) * 260 + (blockIdx.x >> 3);                      \
    int t_ = wg, bi = 0;                                                      \
    while (t_ >= 64 - bi) { t_ -= 64 - bi; ++bi; }                            \
    const int bj = bi + t_;                                                   \
    const int row0 = bi * 128;                                                \
    const int col0 = bj * 128;                                                \
    const bool offdiag = (bj > bi);                                           \
    f32x4 acc[4][4];                                                          \
    _Pragma("unroll")                                                         \
    for (int a = 0; a < 4; ++a)                                               \
        _Pragma("unroll")                                                     \
        for (int b = 0; b < 4; ++b) acc[a][b] = (f32x4){0.f, 0.f, 0.f, 0.f};  \
    float rsq[4][4], csq[4];                                                  \
    _Pragma("unroll")                                                         \
    for (int fm = 0; fm < 4; ++fm)                                            \
        _Pragma("unroll")                                                     \
        for (int r = 0; r < 4; ++r)                                           \
            rsq[fm][r] = sq[row0 + wm * 64 + fm * 16 + lk * 4 + r];           \
    _Pragma("unroll")                                                         \
    for (int fn = 0; fn < 4; ++fn)                                            \
        csq[fn] = sq[col0 + wn * 64 + fn * 16 + l15];

// ---------------------------------------------------------------------------
// Pass 1: denom sums only (duration isolates the K-loop cost).
// ---------------------------------------------------------------------------
__launch_bounds__(256, 2)
__global__ void sum_kernel(const unsigned short* __restrict__ hi,
                           const unsigned short* __restrict__ lo,
                           const float* __restrict__ sq,
                           float* __restrict__ denom) {
    __shared__ __align__(16) unsigned short lds[2 * 16384];  // 64 KB
    DIST_PROLOG()
    DIST_KLOOP()

    float rp[4][4], cp[4];
    #pragma unroll
    for (int a = 0; a < 4; ++a) {
        cp[a] = 0.f;
        #pragma unroll
        for (int b = 0; b < 4; ++b) rp[a][b] = 0.f;
    }
    #pragma unroll
    for (int fm = 0; fm < 4; ++fm)
        #pragma unroll
        for (int fn = 0; fn < 4; ++fn)
            #pragma unroll
            for (int r = 0; r < 4; ++r) {
                float sqd = rsq[fm][r] + csq[fn] - 2.0f * acc[fm][fn][r];
                float d = sqrtf(fmaxf(sqd, 0.0f));
                rp[fm][r] += d;
                if (offdiag) cp[fn] += d;
            }

    #pragma unroll
    for (int fm = 0; fm < 4; ++fm)
        #pragma unroll
        for (int r = 0; r < 4; ++r) {
            float v = rp[fm][r];
            v += __shfl_xor(v, 1, 64);
            v += __shfl_xor(v, 2, 64);
            v += __shfl_xor(v, 4, 64);
            v += __shfl_xor(v, 8, 64);
            if (l15 == 0)
                atomicAdd(&denom[row0 + wm * 64 + fm * 16 + lk * 4 + r], v);
        }
    if (offdiag) {
        #pragma unroll
        for (int fn = 0; fn < 4; ++fn) {
            float v = cp[fn];
            v += __shfl_xor(v, 16, 64);
            v += __shfl_xor(v, 32, 64);
            if (lane < 16)
                atomicAdd(&denom[col0 + wn * 64 + fn * 16 + l15], v);
        }
    }
}

// ---------------------------------------------------------------------------
__global__ void inv_kernel(float* __restrict__ denom) {
    int i = blockIdx.x * 256 + threadIdx.x;
    if (i < NN) denom[i] = 1.0f / denom[i];
}

// ---------------------------------------------------------------------------
// Pass 2: recompute d (bit-identical K-loop), scale by inv, write direct
// tile + LDS-transposed mirror tile.  No atomics.
// ---------------------------------------------------------------------------
__launch_bounds__(256, 2)
__global__ void write_kernel(const unsigned short* __restrict__ hi,
                             const unsigned short* __restrict__ lo,
                             const float* __restrict__ sq,
                             const float* __restrict__ inv,
                             float* __restrict__ out) {
    __shared__ __align__(16) unsigned short lds[2 * 16384];  // 64 KB
    DIST_PROLOG()

    float rinv[4][4];
    #pragma unroll
    for (int fm = 0; fm < 4; ++fm)
        #pragma unroll
        for (int r = 0; r < 4; ++r)
            rinv[fm][r] = inv[row0 + wm * 64 + fm * 16 + lk * 4 + r];

    DIST_KLOOP()

    __syncthreads();   // all waves done with K-loop LDS before ldsT reuse
    float* ldsT = reinterpret_cast<float*>(lds);

    #pragma unroll
    for (int fm = 0; fm < 4; ++fm)
        #pragma unroll
        for (int fn = 0; fn < 4; ++fn)
            #pragma unroll
            for (int r = 0; r < 4; ++r) {
                float sqd = rsq[fm][r] + csq[fn] - 2.0f * acc[fm][fn][r];
                float d = sqrtf(fmaxf(sqd, 0.0f));
                int lr = wm * 64 + fm * 16 + lk * 4 + r;   // local row
                int lc = wn * 64 + fn * 16 + l15;          // local col
                out[(size_t)(row0 + lr) * NN + col0 + lc] = d * rinv[fm][r];
                if (offdiag)
                    ldsT[lc * 128 + (lr ^ ((lc & 31) ^ ((lc & 4) << 2)))] = d;
            }

    if (offdiag) {
        __syncthreads();
        #pragma unroll
        for (int it = 0; it < 64; ++it) {
            int idx = it * 256 + tid;
            int c  = idx >> 7;
            int r_ = idx & 127;
            float d = ldsT[c * 128 + (r_ ^ ((c & 31) ^ ((c & 4) << 2)))];
            out[(size_t)(col0 + c) * NN + row0 + r_] = d * inv[col0 + c];
        }
    }
}

extern "C" void kernel_launch(void* const* d_in, const int* in_sizes, int n_in,
                              void* d_out, int out_size, void* d_ws, size_t ws_size,
                              hipStream_t stream) {
    const float* x = (const float*)d_in[0];
    float* out = (float*)d_out;
    char* ws = (char*)d_ws;
    unsigned short* hi = (unsigned short*)ws;                          // 4 MB
    unsigned short* lo = (unsigned short*)(ws + (size_t)NN * DD * 2);  // 4 MB
    float* sq    = (float*)(ws + (size_t)NN * DD * 4);                 // 32 KB
    float* denom = (float*)(ws + (size_t)NN * DD * 4 + NN * 4);        // 32 KB

    prep_kernel<<<NN, 256, 0, stream>>>(x, hi, lo, sq, denom);
    sum_kernel<<<2080, 256, 0, stream>>>(hi, lo, sq, denom);
    inv_kernel<<<32, 256, 0, stream>>>(denom);
    write_kernel<<<2080, 256, 0, stream>>>(hi, lo, sq, denom, out);
}